// Round 6
// baseline (326.048 us; speedup 1.0000x reference)
//
#include <hip/hip_runtime.h>
#include <stdint.h>

typedef __bf16 bf16_t;
typedef __bf16 bf16x8 __attribute__((ext_vector_type(8)));
typedef __bf16 bf16x4 __attribute__((ext_vector_type(4)));
typedef float floatx4 __attribute__((ext_vector_type(4)));

__device__ __forceinline__ void async_copy16(const bf16_t* g, bf16_t* l) {
  __builtin_amdgcn_global_load_lds(
      (const __attribute__((address_space(1))) void*)g,
      (__attribute__((address_space(3))) void*)l, 16, 0, 0);
}

// ---------- converts ----------
struct CvtSeg { const float* s; bf16_t* d; long n; };
struct CvtArgs { CvtSeg seg[5]; };

__global__ void cvt_multi(CvtArgs a) {
  CvtSeg sg = a.seg[blockIdx.y];
  long i = ((long)blockIdx.x * blockDim.x + threadIdx.x) * 4;
  if (i < sg.n) {
    float4 f = *(const float4*)(sg.s + i);
    bf16x4 o;
    o[0] = (bf16_t)f.x; o[1] = (bf16_t)f.y; o[2] = (bf16_t)f.z; o[3] = (bf16_t)f.w;
    *(bf16x4*)(sg.d + i) = o;
  }
}

// ---------- LDS GEMM core: 128x128 tile, BK=32, dbuf, xor-swizzled staging ----------
__device__ __forceinline__ void gemm_core(
    const bf16_t* __restrict__ Ab, const bf16_t* __restrict__ Bb,
    int lda, int ldb, int nk, bf16_t* As, bf16_t* Bs,
    int m0, int n0, floatx4 (&acc)[4][4]) {
  const int tid  = threadIdx.x;
  const int lane = tid & 63;
  const int w    = tid >> 6;
  const int wr   = w >> 1, wc = w & 1;
  const int quad = lane >> 4, lm = lane & 15;
  const int ar = lane >> 2;
  const int ak = (((lane & 3) ^ ((ar >> 1) & 3))) * 8;
  const bf16_t* ag0 = Ab + (long)(m0 + w * 16 + ar) * lda + ak;
  const bf16_t* ag1 = ag0 + (long)64 * lda;
  const bf16_t* bg0 = Bb + (long)(n0 + w * 16 + ar) * ldb + ak;
  const bf16_t* bg1 = bg0 + (long)64 * ldb;
  const int swz = (lm >> 1) & 3;

  {
    bf16_t* la = As + w * 512;
    bf16_t* lb = Bs + w * 512;
    async_copy16(ag0, la);
    async_copy16(ag1, la + 2048);
    async_copy16(bg0, lb);
    async_copy16(bg1, lb + 2048);
  }
  for (int i = 0; i < nk; i++) {
    __syncthreads();
    if (i + 1 < nk) {
      const int buf = (i + 1) & 1;
      const int k0  = (i + 1) * 32;
      bf16_t* la = As + buf * 4096 + w * 512;
      bf16_t* lb = Bs + buf * 4096 + w * 512;
      async_copy16(ag0 + k0, la);
      async_copy16(ag1 + k0, la + 2048);
      async_copy16(bg0 + k0, lb);
      async_copy16(bg1 + k0, lb + 2048);
    }
    const bf16_t* Ar = As + (i & 1) * 4096;
    const bf16_t* Br = Bs + (i & 1) * 4096;
    bf16x8 afr[4], bfr[4];
#pragma unroll
    for (int r = 0; r < 4; r++)
      afr[r] = *(const bf16x8*)&Ar[(wr * 64 + r * 16 + lm) * 32 + (quad ^ swz) * 8];
#pragma unroll
    for (int c = 0; c < 4; c++)
      bfr[c] = *(const bf16x8*)&Br[(wc * 64 + c * 16 + lm) * 32 + (quad ^ swz) * 8];
#pragma unroll
    for (int r = 0; r < 4; r++)
#pragma unroll
      for (int c = 0; c < 4; c++)
        acc[r][c] = __builtin_amdgcn_mfma_f32_16x16x32_bf16(afr[r], bfr[c], acc[r][c], 0, 0, 0);
  }
}

// ---------- fused q / kT / vT: direct-from-L2 (no LDS) ----------
// Fragments for NT row-major inputs are 16B-contiguous: load straight to VGPRs.
__global__ __launch_bounds__(256) void qkv3(
    const bf16_t* __restrict__ xb,
    const bf16_t* __restrict__ Wq, const bf16_t* __restrict__ Wk, const bf16_t* __restrict__ Wv,
    const float* __restrict__ bq, const float* __restrict__ bk, const float* __restrict__ bv,
    bf16_t* __restrict__ qout, bf16_t* __restrict__ kT, bf16_t* __restrict__ vT) {
  const int L = blockIdx.x + (blockIdx.y << 3) + (blockIdx.z << 7);
  const int V = (L & 7) * 64 + (L >> 3);
  const int batch = V >> 7;
  const int rr_   = V & 127;
  const int n0 = (rr_ & 7) * 128;
  const int m0 = (rr_ >> 3) * 128;

  const int tid = threadIdx.x, lane = tid & 63, w = tid >> 6;
  const int wr = w >> 1, wc = w & 1, quad = lane >> 4, lm = lane & 15;

  // per-lane fragment base pointers (k-offset quad*8 folded in)
  const bf16_t* Abase = xb + (long)batch * (2048L * 1024)
                      + (long)(m0 + wr * 64 + lm) * 1024 + quad * 8;
  const bf16_t* Bq = Wq + (long)(n0 + wc * 64 + lm) * 1024 + quad * 8;
  const bf16_t* Bk = Wk + (long)(n0 + wc * 64 + lm) * 1024 + quad * 8;
  const bf16_t* Bv = Wv + (long)(n0 + wc * 64 + lm) * 1024 + quad * 8;

  floatx4 acc[3][4][4];
#pragma unroll
  for (int p = 0; p < 3; p++)
#pragma unroll
    for (int r = 0; r < 4; r++)
#pragma unroll
      for (int c = 0; c < 4; c++)
        acc[p][r][c] = (floatx4){0.f, 0.f, 0.f, 0.f};

  for (int k0 = 0; k0 < 1024; k0 += 32) {
    bf16x8 afr[4];
#pragma unroll
    for (int r = 0; r < 4; r++)
      afr[r] = *(const bf16x8*)(Abase + r * 16384 + k0);
    {
      bf16x8 bfr[4];
#pragma unroll
      for (int c = 0; c < 4; c++) bfr[c] = *(const bf16x8*)(Bq + c * 16384 + k0);
#pragma unroll
      for (int r = 0; r < 4; r++)
#pragma unroll
        for (int c = 0; c < 4; c++)
          acc[0][r][c] = __builtin_amdgcn_mfma_f32_16x16x32_bf16(afr[r], bfr[c], acc[0][r][c], 0, 0, 0);
    }
    {
      bf16x8 bfr[4];
#pragma unroll
      for (int c = 0; c < 4; c++) bfr[c] = *(const bf16x8*)(Bk + c * 16384 + k0);
#pragma unroll
      for (int r = 0; r < 4; r++)
#pragma unroll
        for (int c = 0; c < 4; c++)
          acc[1][r][c] = __builtin_amdgcn_mfma_f32_16x16x32_bf16(afr[r], bfr[c], acc[1][r][c], 0, 0, 0);
    }
    {
      bf16x8 bfr[4];
#pragma unroll
      for (int c = 0; c < 4; c++) bfr[c] = *(const bf16x8*)(Bv + c * 16384 + k0);
#pragma unroll
      for (int r = 0; r < 4; r++)
#pragma unroll
        for (int c = 0; c < 4; c++)
          acc[2][r][c] = __builtin_amdgcn_mfma_f32_16x16x32_bf16(afr[r], bfr[c], acc[2][r][c], 0, 0, 0);
    }
  }

  const int rowBase = m0 + wr * 64, colBase = n0 + wc * 64;
  {
    bf16_t* C = qout + (long)batch * (2048L * 1024);
#pragma unroll
    for (int r = 0; r < 4; r++) {
      const int row = rowBase + r * 16 + quad * 4;
#pragma unroll
      for (int c = 0; c < 4; c++) {
        const int col = colBase + c * 16 + lm;
        const float bv_ = bq[col];
#pragma unroll
        for (int i = 0; i < 4; i++)
          C[(long)(row + i) * 1024 + col] = (bf16_t)(acc[0][r][c][i] + bv_);
      }
    }
  }
#pragma unroll
  for (int p = 1; p < 3; p++) {
    bf16_t* C = ((p == 1) ? kT : vT) + (long)batch * (1024L * 2048);
    const float* bias = (p == 1) ? bk : bv;
#pragma unroll
    for (int r = 0; r < 4; r++) {
      const int row = rowBase + r * 16 + quad * 4;
#pragma unroll
      for (int c = 0; c < 4; c++) {
        const int col = colBase + c * 16 + lm;
        const float bv_ = bias[col];
        bf16x4 pk;
#pragma unroll
        for (int i = 0; i < 4; i++) pk[i] = (bf16_t)(acc[p][r][c][i] + bv_);
        *(bf16x4*)(C + (long)col * 2048 + row) = pk;
      }
    }
  }
}

// ---------- generic NT GEMM (LDS core) with XCD swizzle ----------
// OUT_MODE 0: bf16 row-major (*alpha, +bias opt); 2: fp32 row-major (+bias)
template<int OUT_MODE, bool HAS_BIAS, int TOTAL, int BPZ, int GNX>
__global__ __launch_bounds__(256) void gemm_nt(
    const bf16_t* __restrict__ A, const bf16_t* __restrict__ B,
    void* __restrict__ C, const float* __restrict__ bias,
    int lda, int ldb, int nk, long sA, long sB, long sC, int ldc, float alpha) {
  __shared__ bf16_t As[8192], Bs[8192];
  const int L = blockIdx.x + gridDim.x * (blockIdx.y + gridDim.y * blockIdx.z);
  const int V = (L & 7) * (TOTAL / 8) + (L >> 3);
  const int batch = V / BPZ;
  const int r_ = V % BPZ;
  const int n0 = (r_ % GNX) * 128;
  const int m0 = (r_ / GNX) * 128;
  const bf16_t* Ab = A + (long)batch * sA;
  const bf16_t* Bb = B + (long)batch * sB;

  floatx4 acc[4][4];
#pragma unroll
  for (int r = 0; r < 4; r++)
#pragma unroll
    for (int c = 0; c < 4; c++) acc[r][c] = (floatx4){0.f, 0.f, 0.f, 0.f};

  gemm_core(Ab, Bb, lda, ldb, nk, As, Bs, m0, n0, acc);

  const int lane = threadIdx.x & 63, w = threadIdx.x >> 6;
  const int wr = w >> 1, wc = w & 1, quad = lane >> 4, lm = lane & 15;
  const int rowBase = m0 + wr * 64, colBase = n0 + wc * 64;

  if (OUT_MODE == 0) {
    bf16_t* Cb = (bf16_t*)C + (long)batch * sC;
#pragma unroll
    for (int r = 0; r < 4; r++) {
      const int row = rowBase + r * 16 + quad * 4;
#pragma unroll
      for (int c = 0; c < 4; c++) {
        const int col = colBase + c * 16 + lm;
        const float bv_ = HAS_BIAS ? bias[col] : 0.f;
#pragma unroll
        for (int i = 0; i < 4; i++)
          Cb[(long)(row + i) * ldc + col] = (bf16_t)(acc[r][c][i] * alpha + bv_);
      }
    }
  } else {
    float* Cf = (float*)C + (long)batch * sC;
#pragma unroll
    for (int r = 0; r < 4; r++) {
      const int row = rowBase + r * 16 + quad * 4;
#pragma unroll
      for (int c = 0; c < 4; c++) {
        const int col = colBase + c * 16 + lm;
        const float bv_ = HAS_BIAS ? bias[col] : 0.f;
#pragma unroll
        for (int i = 0; i < 4; i++)
          Cf[(long)(row + i) * ldc + col] = acc[r][c][i] * alpha + bv_;
      }
    }
  }
}

extern "C" void kernel_launch(void* const* d_in, const int* in_sizes, int n_in,
                              void* d_out, int out_size, void* d_ws, size_t ws_size,
                              hipStream_t stream) {
  const float* x  = (const float*)d_in[0];
  const float* Wq = (const float*)d_in[1];
  const float* bq = (const float*)d_in[2];
  const float* Wk = (const float*)d_in[3];
  const float* bk = (const float*)d_in[4];
  const float* Wv = (const float*)d_in[5];
  const float* bv = (const float*)d_in[6];
  const float* Wo = (const float*)d_in[7];
  const float* bo = (const float*)d_in[8];
  float* out = (float*)d_out;

  const long NX = 8192L * 1024;
  const long NW = 1024L * 1024;
  const long NM = 4L * 1024 * 1024;

  bf16_t* ws  = (bf16_t*)d_ws;
  bf16_t* xb  = ws;                  // NX
  bf16_t* Wqb = xb + NX;
  bf16_t* Wkb = Wqb + NW;
  bf16_t* Wvb = Wkb + NW;
  bf16_t* Wob = Wvb + NW;
  bf16_t* qb  = Wob + NW;            // NX
  bf16_t* kT  = qb + NX;             // NX [B][E][S]
  bf16_t* vT  = kT + NX;             // NX [B][E][S]
  bf16_t* MtTb = vT + NX;            // NM [B][E][E]
  bf16_t* Gb   = xb;                 // reuse: xb dead after qkv3

  CvtArgs ca;
  ca.seg[0] = {x,  xb,  NX};
  ca.seg[1] = {Wq, Wqb, NW};
  ca.seg[2] = {Wk, Wkb, NW};
  ca.seg[3] = {Wv, Wvb, NW};
  ca.seg[4] = {Wo, Wob, NW};
  cvt_multi<<<dim3(NX / 1024, 5), 256, 0, stream>>>(ca);

  // q / kT / vT, direct-from-L2 fragments
  qkv3<<<dim3(8, 16, 4), 256, 0, stream>>>(xb, Wqb, Wkb, Wvb, bq, bk, bv, qb, kT, vT);

  // MtT[f,e] = scale * sum_t kT[f,t]*vT[e,t]; single pass K=2048, bf16 out
  gemm_nt<0, false, 256, 64, 8><<<dim3(8, 8, 4), 256, 0, stream>>>(
      kT, vT, MtTb, nullptr, 2048, 2048, 64,
      1024L * 2048, 1024L * 2048, 1024L * 1024, 1024, 0.125f);

  // G[i,f] = sum_e Wo[i,e] * MtT[f,e]
  gemm_nt<0, false, 256, 64, 8><<<dim3(8, 8, 4), 256, 0, stream>>>(
      Wob, MtTb, Gb, nullptr, 1024, 1024, 32,
      0L, 1024L * 1024, 1024L * 1024, 1024, 1.0f);

  // final[s,i] = sum_f q[s,f] * G[i,f] + bo[i]
  gemm_nt<2, true, 512, 128, 8><<<dim3(8, 16, 4), 256, 0, stream>>>(
      qb, Gb, out, bo, 1024, 1024, 32,
      2048L * 1024, 1024L * 1024, 2048L * 1024, 1024, 1.0f);
}

// Round 7
// 237.574 us; speedup vs baseline: 1.3724x; 1.3724x over previous
//
#include <hip/hip_runtime.h>
#include <stdint.h>

typedef __bf16 bf16_t;
typedef __bf16 bf16x8 __attribute__((ext_vector_type(8)));
typedef __bf16 bf16x4 __attribute__((ext_vector_type(4)));
typedef float floatx4 __attribute__((ext_vector_type(4)));

__device__ __forceinline__ void async_copy16(const bf16_t* g, bf16_t* l) {
  __builtin_amdgcn_global_load_lds(
      (const __attribute__((address_space(1))) void*)g,
      (__attribute__((address_space(3))) void*)l, 16, 0, 0);
}

// ---------- converts ----------
struct CvtSeg { const float* s; bf16_t* d; long n; };
struct CvtArgs { CvtSeg seg[5]; };

__global__ void cvt_multi(CvtArgs a) {
  CvtSeg sg = a.seg[blockIdx.y];
#pragma unroll
  for (int it = 0; it < 4; it++) {
    long i = (((long)blockIdx.x + (long)it * 2048) * 256 + threadIdx.x) * 4;
    if (i < sg.n) {
      float4 f = *(const float4*)(sg.s + i);
      bf16x4 o;
      o[0] = (bf16_t)f.x; o[1] = (bf16_t)f.y; o[2] = (bf16_t)f.z; o[3] = (bf16_t)f.w;
      *(bf16x4*)(sg.d + i) = o;
    }
  }
}

// ---------- fused q / kT / vT: 128x128 tile, LDS dbuf (round-5 proven) ----------
__global__ __launch_bounds__(256, 2) void qkv3(
    const bf16_t* __restrict__ xb,
    const bf16_t* __restrict__ Wq, const bf16_t* __restrict__ Wk, const bf16_t* __restrict__ Wv,
    const float* __restrict__ bq, const float* __restrict__ bk, const float* __restrict__ bv,
    bf16_t* __restrict__ qout, bf16_t* __restrict__ kT, bf16_t* __restrict__ vT) {
  __shared__ bf16_t As[2 * 4096];
  __shared__ bf16_t Bsh[3][2 * 4096];
  const int L = blockIdx.x;
  const int V = (L & 7) * 64 + (L >> 3);
  const int batch = V >> 7;
  const int rr_   = V & 127;
  const int n0 = (rr_ & 7) * 128;
  const int m0 = (rr_ >> 3) * 128;

  const int tid = threadIdx.x, lane = tid & 63, w = tid >> 6;
  const int wr = w >> 1, wc = w & 1, quad = lane >> 4, lm = lane & 15;
  const int ar = lane >> 2;
  const int ak = (((lane & 3) ^ ((ar >> 1) & 3))) * 8;
  const int swz = (lm >> 1) & 3;

  const bf16_t* ag0 = xb + (long)batch * (2048L * 1024) + (long)(m0 + w * 16 + ar) * 1024 + ak;
  const bf16_t* ag1 = ag0 + 64L * 1024;
  const bf16_t* Wp[3] = {Wq, Wk, Wv};
  const bf16_t* bg0[3];
  const bf16_t* bg1[3];
#pragma unroll
  for (int p = 0; p < 3; p++) {
    bg0[p] = Wp[p] + (long)(n0 + w * 16 + ar) * 1024 + ak;
    bg1[p] = bg0[p] + 64L * 1024;
  }

  floatx4 acc[3][4][4];
#pragma unroll
  for (int p = 0; p < 3; p++)
#pragma unroll
    for (int r = 0; r < 4; r++)
#pragma unroll
      for (int c = 0; c < 4; c++)
        acc[p][r][c] = (floatx4){0.f, 0.f, 0.f, 0.f};

  {
    bf16_t* la = As + w * 512;
    async_copy16(ag0, la);
    async_copy16(ag1, la + 2048);
#pragma unroll
    for (int p = 0; p < 3; p++) {
      bf16_t* lb = Bsh[p] + w * 512;
      async_copy16(bg0[p], lb);
      async_copy16(bg1[p], lb + 2048);
    }
  }
  for (int i = 0; i < 32; i++) {
    __syncthreads();
    if (i + 1 < 32) {
      const int buf = (i + 1) & 1, k0 = (i + 1) * 32;
      bf16_t* la = As + buf * 4096 + w * 512;
      async_copy16(ag0 + k0, la);
      async_copy16(ag1 + k0, la + 2048);
#pragma unroll
      for (int p = 0; p < 3; p++) {
        bf16_t* lb = Bsh[p] + buf * 4096 + w * 512;
        async_copy16(bg0[p] + k0, lb);
        async_copy16(bg1[p] + k0, lb + 2048);
      }
    }
    const bf16_t* Ar = As + (i & 1) * 4096;
    bf16x8 afr[4];
#pragma unroll
    for (int r = 0; r < 4; r++)
      afr[r] = *(const bf16x8*)&Ar[(wr * 64 + r * 16 + lm) * 32 + (quad ^ swz) * 8];
#pragma unroll
    for (int p = 0; p < 3; p++) {
      const bf16_t* Br = Bsh[p] + (i & 1) * 4096;
      bf16x8 bfr[4];
#pragma unroll
      for (int c = 0; c < 4; c++)
        bfr[c] = *(const bf16x8*)&Br[(wc * 64 + c * 16 + lm) * 32 + (quad ^ swz) * 8];
#pragma unroll
      for (int r = 0; r < 4; r++)
#pragma unroll
        for (int c = 0; c < 4; c++)
          acc[p][r][c] = __builtin_amdgcn_mfma_f32_16x16x32_bf16(afr[r], bfr[c], acc[p][r][c], 0, 0, 0);
    }
  }

  const int rowBase = m0 + wr * 64, colBase = n0 + wc * 64;
  {
    bf16_t* C = qout + (long)batch * (2048L * 1024);
#pragma unroll
    for (int r = 0; r < 4; r++) {
      const int row = rowBase + r * 16 + quad * 4;
#pragma unroll
      for (int c = 0; c < 4; c++) {
        const int col = colBase + c * 16 + lm;
        const float bv_ = bq[col];
#pragma unroll
        for (int i = 0; i < 4; i++)
          C[(long)(row + i) * 1024 + col] = (bf16_t)(acc[0][r][c][i] + bv_);
      }
    }
  }
#pragma unroll
  for (int p = 1; p < 3; p++) {
    bf16_t* C = ((p == 1) ? kT : vT) + (long)batch * (1024L * 2048);
    const float* bias = (p == 1) ? bk : bv;
#pragma unroll
    for (int r = 0; r < 4; r++) {
      const int row = rowBase + r * 16 + quad * 4;
#pragma unroll
      for (int c = 0; c < 4; c++) {
        const int col = colBase + c * 16 + lm;
        const float bv_ = bias[col];
        bf16x4 pk;
#pragma unroll
        for (int i = 0; i < 4; i++) pk[i] = (bf16_t)(acc[p][r][c][i] + bv_);
        *(bf16x4*)(C + (long)col * 2048 + row) = pk;
      }
    }
  }
}

// ---------- NT GEMM, 128x64 tile, BK=32, dbuf LDS, XCD swizzle ----------
// OUT_MODE 0: bf16 row-major; 2: fp32 row-major (+bias)
template<int OUT_MODE, bool HAS_BIAS, int TOTAL, int BPZ>
__global__ __launch_bounds__(256) void gemm_nt64(
    const bf16_t* __restrict__ A, const bf16_t* __restrict__ B,
    void* __restrict__ C, const float* __restrict__ bias,
    int lda, int ldb, int nk, long sA, long sB, long sC, int ldc, float alpha) {
  __shared__ bf16_t As[2 * 4096];   // 128 x 32 per buffer
  __shared__ bf16_t Bs[2 * 2048];   // 64 x 32 per buffer
  const int L = blockIdx.x;
  const int V = (L & 7) * (TOTAL / 8) + (L >> 3);
  const int batch = V / BPZ;
  const int r_ = V % BPZ;
  const int n0 = (r_ & 15) * 64;
  const int m0 = (r_ >> 4) * 128;

  const int tid = threadIdx.x, lane = tid & 63, w = tid >> 6;
  const int wr = w >> 1, wc = w & 1, quad = lane >> 4, lm = lane & 15;
  const int ar = lane >> 2;
  const int ak = (((lane & 3) ^ ((ar >> 1) & 3))) * 8;
  const int swz = (lm >> 1) & 3;

  const bf16_t* Ab = A + (long)batch * sA;
  const bf16_t* Bb = B + (long)batch * sB;
  const bf16_t* ag0 = Ab + (long)(m0 + w * 16 + ar) * lda + ak;
  const bf16_t* ag1 = ag0 + (long)64 * lda;
  const bf16_t* bg0 = Bb + (long)(n0 + w * 16 + ar) * ldb + ak;

  floatx4 acc[4][2];
#pragma unroll
  for (int r = 0; r < 4; r++)
#pragma unroll
    for (int c = 0; c < 2; c++) acc[r][c] = (floatx4){0.f, 0.f, 0.f, 0.f};

  {
    async_copy16(ag0, As + w * 512);
    async_copy16(ag1, As + w * 512 + 2048);
    async_copy16(bg0, Bs + w * 512);
  }
  for (int i = 0; i < nk; i++) {
    __syncthreads();
    if (i + 1 < nk) {
      const int buf = (i + 1) & 1, k0 = (i + 1) * 32;
      async_copy16(ag0 + k0, As + buf * 4096 + w * 512);
      async_copy16(ag1 + k0, As + buf * 4096 + w * 512 + 2048);
      async_copy16(bg0 + k0, Bs + buf * 2048 + w * 512);
    }
    const bf16_t* Ar = As + (i & 1) * 4096;
    const bf16_t* Br = Bs + (i & 1) * 2048;
    bf16x8 afr[4], bfr[2];
#pragma unroll
    for (int r = 0; r < 4; r++)
      afr[r] = *(const bf16x8*)&Ar[(wr * 64 + r * 16 + lm) * 32 + (quad ^ swz) * 8];
#pragma unroll
    for (int c = 0; c < 2; c++)
      bfr[c] = *(const bf16x8*)&Br[(wc * 32 + c * 16 + lm) * 32 + (quad ^ swz) * 8];
#pragma unroll
    for (int r = 0; r < 4; r++)
#pragma unroll
      for (int c = 0; c < 2; c++)
        acc[r][c] = __builtin_amdgcn_mfma_f32_16x16x32_bf16(afr[r], bfr[c], acc[r][c], 0, 0, 0);
  }

  const int rowBase = m0 + wr * 64, colBase = n0 + wc * 32;
  if (OUT_MODE == 0) {
    bf16_t* Cb = (bf16_t*)C + (long)batch * sC;
#pragma unroll
    for (int r = 0; r < 4; r++) {
      const int row = rowBase + r * 16 + quad * 4;
#pragma unroll
      for (int c = 0; c < 2; c++) {
        const int col = colBase + c * 16 + lm;
        const float bv_ = HAS_BIAS ? bias[col] : 0.f;
#pragma unroll
        for (int i = 0; i < 4; i++)
          Cb[(long)(row + i) * ldc + col] = (bf16_t)(acc[r][c][i] * alpha + bv_);
      }
    }
  } else {
    float* Cf = (float*)C + (long)batch * sC;
#pragma unroll
    for (int r = 0; r < 4; r++) {
      const int row = rowBase + r * 16 + quad * 4;
#pragma unroll
      for (int c = 0; c < 2; c++) {
        const int col = colBase + c * 16 + lm;
        const float bv_ = HAS_BIAS ? bias[col] : 0.f;
#pragma unroll
        for (int i = 0; i < 4; i++)
          Cf[(long)(row + i) * ldc + col] = acc[r][c][i] * alpha + bv_;
      }
    }
  }
}

extern "C" void kernel_launch(void* const* d_in, const int* in_sizes, int n_in,
                              void* d_out, int out_size, void* d_ws, size_t ws_size,
                              hipStream_t stream) {
  const float* x  = (const float*)d_in[0];
  const float* Wq = (const float*)d_in[1];
  const float* bq = (const float*)d_in[2];
  const float* Wk = (const float*)d_in[3];
  const float* bk = (const float*)d_in[4];
  const float* Wv = (const float*)d_in[5];
  const float* bv = (const float*)d_in[6];
  const float* Wo = (const float*)d_in[7];
  const float* bo = (const float*)d_in[8];
  float* out = (float*)d_out;

  const long NX = 8192L * 1024;
  const long NW = 1024L * 1024;
  const long NM = 4L * 1024 * 1024;

  bf16_t* ws  = (bf16_t*)d_ws;
  bf16_t* xb  = ws;                  // NX
  bf16_t* Wqb = xb + NX;
  bf16_t* Wkb = Wqb + NW;
  bf16_t* Wvb = Wkb + NW;
  bf16_t* Wob = Wvb + NW;
  bf16_t* qb  = Wob + NW;            // NX
  bf16_t* kT  = qb + NX;             // NX [B][E][S]
  bf16_t* vT  = kT + NX;             // NX [B][E][S]
  bf16_t* MtTb = vT + NX;            // NM [B][E][E]
  bf16_t* Gb   = xb;                 // reuse: xb dead after qkv3

  CvtArgs ca;
  ca.seg[0] = {x,  xb,  NX};
  ca.seg[1] = {Wq, Wqb, NW};
  ca.seg[2] = {Wk, Wkb, NW};
  ca.seg[3] = {Wv, Wvb, NW};
  ca.seg[4] = {Wo, Wob, NW};
  cvt_multi<<<dim3(2048, 5), 256, 0, stream>>>(ca);

  // q / kT / vT fused, LDS dbuf (round-5 proven structure)
  qkv3<<<dim3(512), 256, 0, stream>>>(xb, Wqb, Wkb, Wvb, bq, bk, bv, qb, kT, vT);

  // MtT[f,e] = scale * sum_t kT[f,t]*vT[e,t]; K=2048, 512 blocks (2/CU)
  gemm_nt64<0, false, 512, 128><<<dim3(512), 256, 0, stream>>>(
      kT, vT, MtTb, nullptr, 2048, 2048, 64,
      1024L * 2048, 1024L * 2048, 1024L * 1024, 1024, 0.125f);

  // G[i,f] = sum_e Wo[i,e] * MtT[f,e]; 512 blocks (2/CU)
  gemm_nt64<0, false, 512, 128><<<dim3(512), 256, 0, stream>>>(
      Wob, MtTb, Gb, nullptr, 1024, 1024, 32,
      0L, 1024L * 1024, 1024L * 1024, 1024, 1.0f);

  // final[s,i] = sum_f q[s,f] * G[i,f] + bo[i]; 1024 blocks (4/CU)
  gemm_nt64<2, true, 1024, 256><<<dim3(1024), 256, 0, stream>>>(
      qb, Gb, out, bo, 1024, 1024, 32,
      2048L * 1024, 1024L * 1024, 2048L * 1024, 1024, 1.0f);
}